// Round 5
// baseline (345.873 us; speedup 1.0000x reference)
//
#include <hip/hip_runtime.h>
#include <hip/hip_bf16.h>
#include <stdint.h>

#define CHUNKC 32
#define PRIORC 64
#define POSEC 512
#define PREDC 128
#define NB 2048
#define K1 (CHUNKC*POSEC)   // 16384
#define KS 8                // split-K factor for gemm1
#define KCH (K1/KS)         // 2048

typedef __attribute__((ext_vector_type(8))) short bf16x8;
typedef __attribute__((ext_vector_type(4))) float f32x4;

__device__ __forceinline__ unsigned short f2b(float f) {
    union { float f; unsigned int u; } x; x.f = f;
    unsigned int r = x.u + 0x7fffu + ((x.u >> 16) & 1u);
    return (unsigned short)(r >> 16);
}

__device__ __forceinline__ void gload_lds16(const void* g, void* l) {
    __builtin_amdgcn_global_load_lds(
        (const __attribute__((address_space(1))) unsigned int*)g,
        (__attribute__((address_space(3))) unsigned int*)l, 16, 0, 0);
}

// ---------------- cvt_all: x-slice, W1, W2 -> bf16 (round-2 proven) ----------------
#define XN4   8388608   // 2048*4096 float4 of x-slice
#define W1N4  2097152   // 512*16384/4
#define W2N4  65536     // 512*512/4
__global__ __launch_bounds__(256) void cvt_all_kernel(const float4* __restrict__ init,
                                                      const float4* __restrict__ W1,
                                                      const float4* __restrict__ W2,
                                                      ushort4* __restrict__ xb,
                                                      ushort4* __restrict__ w1b,
                                                      ushort4* __restrict__ w2b) {
    const int64_t n = XN4 + W1N4 + W2N4;
    const int64_t stride = (int64_t)gridDim.x * blockDim.x;
    for (int64_t i = (int64_t)blockIdx.x * blockDim.x + threadIdx.x; i < n; i += stride) {
        float4 v; ushort4* dst;
        if (i < XN4) {
            int64_t b = i >> 12, r = i & 4095;
            v = init[b * 8192 + 4096 + r];
            dst = xb + i;
        } else if (i < XN4 + W1N4) {
            v = W1[i - XN4];
            dst = w1b + (i - XN4);
        } else {
            v = W2[i - XN4 - W1N4];
            dst = w2b + (i - XN4 - W1N4);
        }
        *dst = make_ushort4(f2b(v.x), f2b(v.y), f2b(v.z), f2b(v.w));
    }
}

// ---------------- GEMM1: partials of x @ W1^T ----------------
// 64x128 tile, BK=64, 4 waves (2x2, each 32x64 out), gload_lds both operands.
// grid = 32 mt * 4 nt * 8 ks = 1024 blocks -> 4/CU (launch_bounds(256,4)).
// XCD-chunked swizzle: phys bid -> orig = (bid%8)*128 + bid/8; mt fastest.
__global__ __launch_bounds__(256, 4) void gemm1_kernel(const ushort* __restrict__ xb,
                                                       const ushort* __restrict__ w1b,
                                                       float* __restrict__ part) {
    __shared__ ushort As[64][64];    // 8 KB, linear (global_load_lds)
    __shared__ ushort Bs[128][64];   // 16 KB
    const int t = threadIdx.x;
    const int l = t & 63, wid = t >> 6;
    const int wr = wid >> 1, wc = wid & 1;          // 2x2 waves; wave owns 32x64
    const int orig = (blockIdx.x & 7) * 128 + (blockIdx.x >> 3);
    const int mt = orig & 31, nt = (orig >> 5) & 3, ks = orig >> 7;

    f32x4 acc[2][4] = {};

    const ushort* aG = xb  + (int64_t)(mt * 64)  * K1 + ks * KCH;
    const ushort* bG = w1b + (int64_t)(nt * 128) * K1 + ks * KCH;
    const int srow = t >> 3, scol = (t & 7) * 8;    // 32 rows x 8 cols of 16B per chunk

    const int fr = l & 15, fq = l >> 4;

    for (int k0 = 0; k0 < KCH; k0 += 64) {
        // A: 2 chunks of 32 rows
#pragma unroll
        for (int i = 0; i < 2; ++i)
            gload_lds16(aG + (int64_t)(i * 32 + srow) * K1 + k0 + scol,
                        (char*)&As[0][0] + i * 4096 + wid * 1024);
        // B: 4 chunks of 32 rows
#pragma unroll
        for (int i = 0; i < 4; ++i)
            gload_lds16(bG + (int64_t)(i * 32 + srow) * K1 + k0 + scol,
                        (char*)&Bs[0][0] + i * 4096 + wid * 1024);
        __syncthreads();
#pragma unroll
        for (int k2 = 0; k2 < 2; ++k2) {
            bf16x8 a[2], b[4];
#pragma unroll
            for (int m = 0; m < 2; ++m)
                a[m] = *(const bf16x8*)&As[wr * 32 + m * 16 + fr][k2 * 32 + fq * 8];
#pragma unroll
            for (int n = 0; n < 4; ++n)
                b[n] = *(const bf16x8*)&Bs[wc * 64 + n * 16 + fr][k2 * 32 + fq * 8];
#pragma unroll
            for (int m = 0; m < 2; ++m)
#pragma unroll
                for (int n = 0; n < 4; ++n)
                    acc[m][n] = __builtin_amdgcn_mfma_f32_16x16x32_bf16(a[m], b[n], acc[m][n], 0, 0, 0);
        }
        __syncthreads();
    }

    float* P = part + (int64_t)ks * NB * POSEC;
    const int mbase = mt * 64 + wr * 32, nbase = nt * 128 + wc * 64;
#pragma unroll
    for (int m = 0; m < 2; ++m)
#pragma unroll
        for (int n = 0; n < 4; ++n) {
            int row0 = mbase + m * 16 + fq * 4;
            int col  = nbase + n * 16 + fr;
#pragma unroll
            for (int r = 0; r < 4; ++r)
                P[(int64_t)(row0 + r) * POSEC + col] = acc[m][n][r];
        }
}

// ---------------- reduce: A2 = bf16(sum_ks part + b1) ----------------
__global__ __launch_bounds__(256) void reduce_kernel(const float4* __restrict__ part,
                                                     const float* __restrict__ b1,
                                                     ushort4* __restrict__ A2) {
    const int i4 = blockIdx.x * 256 + threadIdx.x;      // 262144 float4 total
    float4 s = part[i4];
#pragma unroll
    for (int k = 1; k < KS; ++k) {
        float4 p = part[(int64_t)k * 262144 + i4];
        s.x += p.x; s.y += p.y; s.z += p.z; s.w += p.w;
    }
    const int col = (i4 * 4) & 511;
    float4 bv = *(const float4*)&b1[col];
    A2[i4] = make_ushort4(f2b(s.x + bv.x), f2b(s.y + bv.y), f2b(s.z + bv.z), f2b(s.w + bv.w));
}

// ---------------- GEMM2: mem = A2 @ W2b^T + b2 (round-2 proven) ----------------
__global__ __launch_bounds__(256) void gemm2_kernel(const ushort* __restrict__ A2,
                                                    const ushort* __restrict__ w2b,
                                                    const float* __restrict__ b2,
                                                    float* __restrict__ mem) {
    __shared__ ushort As[64][64];
    __shared__ ushort Bs[64][64];
    const int t = threadIdx.x;
    const int l = t & 63, wid = t >> 6;
    const int wr = wid >> 1, wc = wid & 1;
    const int mt = blockIdx.x >> 3, nt = blockIdx.x & 7;

    f32x4 acc[2][2] = {};
    const ushort* aG = A2  + (int64_t)(mt * 64) * POSEC;
    const ushort* bG = w2b + (int64_t)(nt * 64) * POSEC;
    const int srow = t >> 3, scol = (t & 7) * 8;
    const int fr = l & 15, fq = l >> 4;

    for (int k0 = 0; k0 < POSEC; k0 += 64) {
#pragma unroll
        for (int i = 0; i < 2; ++i) {
            gload_lds16(aG + (int64_t)(i * 32 + srow) * POSEC + k0 + scol,
                        (char*)&As[0][0] + i * 4096 + wid * 1024);
            gload_lds16(bG + (int64_t)(i * 32 + srow) * POSEC + k0 + scol,
                        (char*)&Bs[0][0] + i * 4096 + wid * 1024);
        }
        __syncthreads();
#pragma unroll
        for (int k2 = 0; k2 < 2; ++k2) {
            bf16x8 a[2], b[2];
#pragma unroll
            for (int m = 0; m < 2; ++m)
                a[m] = *(const bf16x8*)&As[wr * 32 + m * 16 + fr][k2 * 32 + fq * 8];
#pragma unroll
            for (int n = 0; n < 2; ++n)
                b[n] = *(const bf16x8*)&Bs[wc * 32 + n * 16 + fr][k2 * 32 + fq * 8];
#pragma unroll
            for (int m = 0; m < 2; ++m)
#pragma unroll
                for (int n = 0; n < 2; ++n)
                    acc[m][n] = __builtin_amdgcn_mfma_f32_16x16x32_bf16(a[m], b[n], acc[m][n], 0, 0, 0);
        }
        __syncthreads();
    }

    const int mbase = mt * 64 + wr * 32, nbase = nt * 64 + wc * 32;
#pragma unroll
    for (int m = 0; m < 2; ++m)
#pragma unroll
        for (int n = 0; n < 2; ++n) {
            int row0 = mbase + m * 16 + fq * 4;
            int col  = nbase + n * 16 + fr;
            float bias = b2[col];
#pragma unroll
            for (int r = 0; r < 4; ++r)
                mem[(int64_t)(row0 + r) * POSEC + col] = acc[m][n][r] + bias;
        }
}

// ---------------- score + sigmoid + blend + copy (round-2 proven) ----------------
__global__ __launch_bounds__(256) void blend_kernel(const float* __restrict__ pred,
                                                    const float* __restrict__ mem,
                                                    float* __restrict__ out) {
    const int b = blockIdx.x;
    const int t = threadIdx.x;
    __shared__ float sm[POSEC];
    __shared__ float sg[CHUNKC];

    sm[t]       = mem[(int64_t)b * POSEC + t];
    sm[t + 256] = mem[(int64_t)b * POSEC + 256 + t];
    __syncthreads();

    const int l = t & 63, wid = t >> 6;
    const float4* sm4 = (const float4*)sm;
    const float4* p4 = (const float4*)pred + (int64_t)b * 16384;
    float4* o4 = (float4*)out + (int64_t)b * 16384;

#pragma unroll
    for (int ci = 0; ci < 8; ++ci) {
        int c = wid * 8 + ci;
        float4 h0 = p4[c * 128 + l * 2];
        float4 h1 = p4[c * 128 + l * 2 + 1];
        float4 m0 = sm4[l * 2];
        float4 m1 = sm4[l * 2 + 1];
        float s = h0.x * m0.x + h0.y * m0.y + h0.z * m0.z + h0.w * m0.w
                + h1.x * m1.x + h1.y * m1.y + h1.z * m1.z + h1.w * m1.w;
#pragma unroll
        for (int o = 32; o; o >>= 1) s += __shfl_xor(s, o);
        if (l == 0) sg[c] = 1.0f / (1.0f + expf(-s));
    }
    __syncthreads();

#pragma unroll
    for (int i = 0; i < 16; ++i) {
        int idx = i * 256 + t;
        int row = idx >> 7, c4 = idx & 127;
        float g = sg[row];
        float4 h = p4[idx];
        float4 m = sm4[c4];
        float4 r;
        r.x = g * h.x + (1.0f - g) * m.x;
        r.y = g * h.y + (1.0f - g) * m.y;
        r.z = g * h.z + (1.0f - g) * m.z;
        r.w = g * h.w + (1.0f - g) * m.w;
        o4[idx] = r;
    }
#pragma unroll
    for (int i = 0; i < 48; ++i) {
        int idx = 4096 + i * 256 + t;
        o4[idx] = p4[idx];
    }
}

// ---------------- launch ----------------

extern "C" void kernel_launch(void* const* d_in, const int* in_sizes, int n_in,
                              void* d_out, int out_size, void* d_ws, size_t ws_size,
                              hipStream_t stream) {
    const float* init = (const float*)d_in[0];
    const float* pred = (const float*)d_in[1];
    const float* W1   = (const float*)d_in[2];
    const float* b1   = (const float*)d_in[3];
    const float* W2   = (const float*)d_in[4];
    const float* b2   = (const float*)d_in[5];
    float* out = (float*)d_out;

    char* ws = (char*)d_ws;
    ushort* xb   = (ushort*)(ws);                       // 67108864 B
    ushort* w1b  = (ushort*)(ws + 67108864);            // 16777216 B
    ushort* w2b  = (ushort*)(ws + 83886080);            //   524288 B
    float*  part = (float*) (ws + 84410368);            // 33554432 B (8 x 2048 x 512 f32)
    ushort* A2   = (ushort*)(ws + 117964800);           //  2097152 B
    float*  mem  = (float*) (ws + 120061952);           //  4194304 B

    cvt_all_kernel<<<2560, 256, 0, stream>>>((const float4*)init, (const float4*)W1,
                                             (const float4*)W2,
                                             (ushort4*)xb, (ushort4*)w1b, (ushort4*)w2b);
    gemm1_kernel<<<1024, 256, 0, stream>>>(xb, w1b, part);
    reduce_kernel<<<1024, 256, 0, stream>>>((const float4*)part, b1, (ushort4*)A2);
    gemm2_kernel<<<256, 256, 0, stream>>>(A2, w2b, b2, mem);
    blend_kernel<<<NB, 256, 0, stream>>>(pred, mem, out);
}

// Round 6
// 333.856 us; speedup vs baseline: 1.0360x; 1.0360x over previous
//
#include <hip/hip_runtime.h>
#include <hip/hip_bf16.h>
#include <stdint.h>

#define CHUNKC 32
#define PRIORC 64
#define POSEC 512
#define PREDC 128
#define NB 2048
#define K1 (CHUNKC*POSEC)   // 16384

typedef __attribute__((ext_vector_type(8))) short bf16x8;
typedef __attribute__((ext_vector_type(4))) float f32x4;
typedef __attribute__((ext_vector_type(4))) float f4v;
typedef __attribute__((ext_vector_type(4))) unsigned short u16x4;

__device__ __forceinline__ unsigned short f2b(float f) {
    union { float f; unsigned int u; } x; x.f = f;
    unsigned int r = x.u + 0x7fffu + ((x.u >> 16) & 1u);
    return (unsigned short)(r >> 16);
}

__device__ __forceinline__ void gload_lds16(const void* g, void* l) {
    __builtin_amdgcn_global_load_lds(
        (const __attribute__((address_space(1))) unsigned int*)g,
        (__attribute__((address_space(3))) unsigned int*)l, 16, 0, 0);
}

// ---------------- cvt_all: x-slice, W1, W2 -> bf16 (nontemporal streams) ----------------
#define XN4   8388608   // 2048*4096 float4 of x-slice
#define W1N4  2097152   // 512*16384/4
#define W2N4  65536     // 512*512/4
__global__ __launch_bounds__(256) void cvt_all_kernel(const f4v* __restrict__ init,
                                                      const f4v* __restrict__ W1,
                                                      const f4v* __restrict__ W2,
                                                      u16x4* __restrict__ xb,
                                                      u16x4* __restrict__ w1b,
                                                      u16x4* __restrict__ w2b) {
    const int64_t n = XN4 + W1N4 + W2N4;
    const int64_t stride = (int64_t)gridDim.x * blockDim.x;
    for (int64_t i = (int64_t)blockIdx.x * blockDim.x + threadIdx.x; i < n; i += stride) {
        f4v v; u16x4* dst;
        if (i < XN4) {
            int64_t b = i >> 12, r = i & 4095;
            v = __builtin_nontemporal_load(init + b * 8192 + 4096 + r);
            dst = xb + i;
        } else if (i < XN4 + W1N4) {
            v = __builtin_nontemporal_load(W1 + (i - XN4));
            dst = w1b + (i - XN4);
        } else {
            v = __builtin_nontemporal_load(W2 + (i - XN4 - W1N4));
            dst = w2b + (i - XN4 - W1N4);
        }
        u16x4 o;
        o[0] = f2b(v[0]); o[1] = f2b(v[1]); o[2] = f2b(v[2]); o[3] = f2b(v[3]);
        __builtin_nontemporal_store(o, dst);
    }
}

// ---------------- GEMM1: partials of x @ W1^T ----------------
// 256x256 tile, BK=64, 8 waves (2x4; each wave 128x64 out), gload_lds both operands.
// grid = 8 mt * 2 nt * KS ks; XCD-chunked bijective swizzle (grid % 8 == 0).
template<int KSv>
__global__ __launch_bounds__(512) void gemm1_kernel(const ushort* __restrict__ xb,
                                                    const ushort* __restrict__ w1b,
                                                    float* __restrict__ part) {
    __shared__ ushort As[256][64];   // 32 KB, linear (global_load_lds)
    __shared__ ushort Bs[256][64];   // 32 KB
    const int t = threadIdx.x;
    const int l = t & 63, wid = t >> 6;
    const int wr = wid >> 2, wc = wid & 3;          // 2x4 waves; wave owns 128x64
    const int cpx = (16 * KSv) >> 3;                // blocks per XCD chunk
    const int orig = (blockIdx.x & 7) * cpx + (blockIdx.x >> 3);
    const int mt = orig & 7, nt = (orig >> 3) & 1, ks = orig >> 4;
    const int KCHv = K1 / KSv;

    f32x4 acc[8][4] = {};

    const ushort* aG = xb  + (int64_t)(mt * 256) * K1 + ks * KCHv;
    const ushort* bG = w1b + (int64_t)(nt * 256) * K1 + ks * KCHv;
    const int srow = t >> 3, scol = (t & 7) * 8;    // 64 rows x 8 cols of 16B per chunk

    const int fr = l & 15, fq = l >> 4;

    for (int k0 = 0; k0 < KCHv; k0 += 64) {
#pragma unroll
        for (int i = 0; i < 4; ++i) {               // 4 chunks of 64 rows, A and B
            gload_lds16(aG + (int64_t)(i * 64 + srow) * K1 + k0 + scol,
                        (char*)&As[0][0] + i * 8192 + wid * 1024);
            gload_lds16(bG + (int64_t)(i * 64 + srow) * K1 + k0 + scol,
                        (char*)&Bs[0][0] + i * 8192 + wid * 1024);
        }
        __syncthreads();
#pragma unroll
        for (int k2 = 0; k2 < 2; ++k2) {
            bf16x8 a[8], b[4];
#pragma unroll
            for (int m = 0; m < 8; ++m)
                a[m] = *(const bf16x8*)&As[wr * 128 + m * 16 + fr][k2 * 32 + fq * 8];
#pragma unroll
            for (int n = 0; n < 4; ++n)
                b[n] = *(const bf16x8*)&Bs[wc * 64 + n * 16 + fr][k2 * 32 + fq * 8];
#pragma unroll
            for (int m = 0; m < 8; ++m)
#pragma unroll
                for (int n = 0; n < 4; ++n)
                    acc[m][n] = __builtin_amdgcn_mfma_f32_16x16x32_bf16(a[m], b[n], acc[m][n], 0, 0, 0);
        }
        __syncthreads();
    }

    float* P = part + (int64_t)ks * NB * POSEC;
    const int mbase = mt * 256 + wr * 128, nbase = nt * 256 + wc * 64;
#pragma unroll
    for (int m = 0; m < 8; ++m)
#pragma unroll
        for (int n = 0; n < 4; ++n) {
            int row0 = mbase + m * 16 + fq * 4;
            int col  = nbase + n * 16 + fr;
#pragma unroll
            for (int r = 0; r < 4; ++r)
                P[(int64_t)(row0 + r) * POSEC + col] = acc[m][n][r];
        }
}

// ---------------- reduce: A2 = bf16(sum_ks part + b1) ----------------
template<int KSv>
__global__ __launch_bounds__(256) void reduce_kernel(const float4* __restrict__ part,
                                                     const float* __restrict__ b1,
                                                     ushort4* __restrict__ A2) {
    const int i4 = blockIdx.x * 256 + threadIdx.x;      // 262144 float4 total
    float4 s = part[i4];
#pragma unroll
    for (int k = 1; k < KSv; ++k) {
        float4 p = part[(int64_t)k * 262144 + i4];
        s.x += p.x; s.y += p.y; s.z += p.z; s.w += p.w;
    }
    const int col = (i4 * 4) & 511;
    float4 bv = *(const float4*)&b1[col];
    A2[i4] = make_ushort4(f2b(s.x + bv.x), f2b(s.y + bv.y), f2b(s.z + bv.z), f2b(s.w + bv.w));
}

// ---------------- GEMM2: mem = A2 @ W2b^T + b2 (round-2 proven) ----------------
__global__ __launch_bounds__(256) void gemm2_kernel(const ushort* __restrict__ A2,
                                                    const ushort* __restrict__ w2b,
                                                    const float* __restrict__ b2,
                                                    float* __restrict__ mem) {
    __shared__ ushort As[64][64];
    __shared__ ushort Bs[64][64];
    const int t = threadIdx.x;
    const int l = t & 63, wid = t >> 6;
    const int wr = wid >> 1, wc = wid & 1;
    const int mt = blockIdx.x >> 3, nt = blockIdx.x & 7;

    f32x4 acc[2][2] = {};
    const ushort* aG = A2  + (int64_t)(mt * 64) * POSEC;
    const ushort* bG = w2b + (int64_t)(nt * 64) * POSEC;
    const int srow = t >> 3, scol = (t & 7) * 8;
    const int fr = l & 15, fq = l >> 4;

    for (int k0 = 0; k0 < POSEC; k0 += 64) {
#pragma unroll
        for (int i = 0; i < 2; ++i) {
            gload_lds16(aG + (int64_t)(i * 32 + srow) * POSEC + k0 + scol,
                        (char*)&As[0][0] + i * 4096 + wid * 1024);
            gload_lds16(bG + (int64_t)(i * 32 + srow) * POSEC + k0 + scol,
                        (char*)&Bs[0][0] + i * 4096 + wid * 1024);
        }
        __syncthreads();
#pragma unroll
        for (int k2 = 0; k2 < 2; ++k2) {
            bf16x8 a[2], b[2];
#pragma unroll
            for (int m = 0; m < 2; ++m)
                a[m] = *(const bf16x8*)&As[wr * 32 + m * 16 + fr][k2 * 32 + fq * 8];
#pragma unroll
            for (int n = 0; n < 2; ++n)
                b[n] = *(const bf16x8*)&Bs[wc * 32 + n * 16 + fr][k2 * 32 + fq * 8];
#pragma unroll
            for (int m = 0; m < 2; ++m)
#pragma unroll
                for (int n = 0; n < 2; ++n)
                    acc[m][n] = __builtin_amdgcn_mfma_f32_16x16x32_bf16(a[m], b[n], acc[m][n], 0, 0, 0);
        }
        __syncthreads();
    }

    const int mbase = mt * 64 + wr * 32, nbase = nt * 64 + wc * 32;
#pragma unroll
    for (int m = 0; m < 2; ++m)
#pragma unroll
        for (int n = 0; n < 2; ++n) {
            int row0 = mbase + m * 16 + fq * 4;
            int col  = nbase + n * 16 + fr;
            float bias = b2[col];
#pragma unroll
            for (int r = 0; r < 4; ++r)
                mem[(int64_t)(row0 + r) * POSEC + col] = acc[m][n][r] + bias;
        }
}

// ---------------- score + sigmoid + blend + copy (round-2 + nt tail) ----------------
__global__ __launch_bounds__(256) void blend_kernel(const float* __restrict__ pred,
                                                    const float* __restrict__ mem,
                                                    float* __restrict__ out) {
    const int b = blockIdx.x;
    const int t = threadIdx.x;
    __shared__ float sm[POSEC];
    __shared__ float sg[CHUNKC];

    sm[t]       = mem[(int64_t)b * POSEC + t];
    sm[t + 256] = mem[(int64_t)b * POSEC + 256 + t];
    __syncthreads();

    const int l = t & 63, wid = t >> 6;
    const float4* sm4 = (const float4*)sm;
    const float4* p4 = (const float4*)pred + (int64_t)b * 16384;
    float4* o4 = (float4*)out + (int64_t)b * 16384;

#pragma unroll
    for (int ci = 0; ci < 8; ++ci) {
        int c = wid * 8 + ci;
        float4 h0 = p4[c * 128 + l * 2];
        float4 h1 = p4[c * 128 + l * 2 + 1];
        float4 m0 = sm4[l * 2];
        float4 m1 = sm4[l * 2 + 1];
        float s = h0.x * m0.x + h0.y * m0.y + h0.z * m0.z + h0.w * m0.w
                + h1.x * m1.x + h1.y * m1.y + h1.z * m1.z + h1.w * m1.w;
#pragma unroll
        for (int o = 32; o; o >>= 1) s += __shfl_xor(s, o);
        if (l == 0) sg[c] = 1.0f / (1.0f + expf(-s));
    }
    __syncthreads();

#pragma unroll
    for (int i = 0; i < 16; ++i) {
        int idx = i * 256 + t;
        int row = idx >> 7, c4 = idx & 127;
        float g = sg[row];
        float4 h = p4[idx];
        float4 m = sm4[c4];
        float4 r;
        r.x = g * h.x + (1.0f - g) * m.x;
        r.y = g * h.y + (1.0f - g) * m.y;
        r.z = g * h.z + (1.0f - g) * m.z;
        r.w = g * h.w + (1.0f - g) * m.w;
        o4[idx] = r;
    }
    // tail copy rows 32..127: one-touch stream, nontemporal
#pragma unroll
    for (int i = 0; i < 48; ++i) {
        int idx = 4096 + i * 256 + t;
        f4v h = __builtin_nontemporal_load((const f4v*)p4 + idx);
        __builtin_nontemporal_store(h, (f4v*)o4 + idx);
    }
}

// ---------------- launch ----------------

extern "C" void kernel_launch(void* const* d_in, const int* in_sizes, int n_in,
                              void* d_out, int out_size, void* d_ws, size_t ws_size,
                              hipStream_t stream) {
    const float* init = (const float*)d_in[0];
    const float* pred = (const float*)d_in[1];
    const float* W1   = (const float*)d_in[2];
    const float* b1   = (const float*)d_in[3];
    const float* W2   = (const float*)d_in[4];
    const float* b2   = (const float*)d_in[5];
    float* out = (float*)d_out;

    // KS=16 needs 157,810,688 B of ws; fall back to KS=8 (124,256,256 B, round-2 layout) if short.
    const int KS = (ws_size >= 157810688u) ? 16 : 8;

    char* ws = (char*)d_ws;
    ushort* xb   = (ushort*)(ws);                               // 67108864 B
    ushort* w1b  = (ushort*)(ws + 67108864);                    // 16777216 B
    ushort* w2b  = (ushort*)(ws + 83886080);                    //   524288 B
    float*  part = (float*) (ws + 84410368);                    // KS*4194304 B
    char*   after = ws + 84410368 + (size_t)KS * 4194304;
    ushort* A2   = (ushort*)(after);                            //  2097152 B
    float*  mem  = (float*) (after + 2097152);                  //  4194304 B

    cvt_all_kernel<<<2560, 256, 0, stream>>>((const f4v*)init, (const f4v*)W1,
                                             (const f4v*)W2,
                                             (u16x4*)xb, (u16x4*)w1b, (u16x4*)w2b);
    if (KS == 16) {
        gemm1_kernel<16><<<256, 512, 0, stream>>>(xb, w1b, part);
        reduce_kernel<16><<<1024, 256, 0, stream>>>((const float4*)part, b1, (ushort4*)A2);
    } else {
        gemm1_kernel<8><<<128, 512, 0, stream>>>(xb, w1b, part);
        reduce_kernel<8><<<1024, 256, 0, stream>>>((const float4*)part, b1, (ushort4*)A2);
    }
    gemm2_kernel<<<256, 256, 0, stream>>>(A2, w2b, b2, mem);
    blend_kernel<<<NB, 256, 0, stream>>>(pred, mem, out);
}